// Round 1
// baseline (233.890 us; speedup 1.0000x reference)
//
#include <hip/hip_runtime.h>

// 21-qubit statevector policy net.
// ws layout: psi (2^21 float2, 16MB) | mats (84*4 float2) @16MB | partials (256*22 f32) @16MB+4K
#define NQ 21
#define DIM (1 << NQ)
#define NL 4
#define ADIM 18

__device__ __forceinline__ float2 cmul(float2 a, float2 b) {
    return make_float2(a.x * b.x - a.y * b.y, a.x * b.y + a.y * b.x);
}
// u0*a + u1*b
__device__ __forceinline__ float2 cfma2(float2 u0, float2 a, float2 u1, float2 b) {
    return make_float2(u0.x * a.x - u0.y * a.y + u1.x * b.x - u1.y * b.y,
                       u0.x * a.y + u0.y * a.x + u1.x * b.y + u1.y * b.x);
}

// suffix-parity over 8 bits: out_k = XOR_{j>=k} h_j  (forward map of the B-local CNOT sub-chain)
__device__ __forceinline__ int pxor8(int x) {
    x ^= x >> 1; x ^= x >> 2; x ^= x >> 4;
    return x & 0xFF;
}

// Fused per-(layer,qubit) unitary U = RZ(c) * RY(b) * RX(a)
__global__ void k_mats(const float* __restrict__ p, float2* __restrict__ mats) {
    int g = blockIdx.x * blockDim.x + threadIdx.x;
    if (g >= NL * NQ) return;
    const float* ang = p + g * 3;
    float a = ang[0], b = ang[1], c = ang[2];
    float ca = cosf(0.5f * a), sa = sinf(0.5f * a);
    float cb = cosf(0.5f * b), sb = sinf(0.5f * b);
    float cc = cosf(0.5f * c), sc = sinf(0.5f * c);
    // M = RY*RX
    float2 m00 = make_float2(cb * ca,  sb * sa);
    float2 m01 = make_float2(-sb * ca, -cb * sa);
    float2 m10 = make_float2(sb * ca,  -cb * sa);
    float2 m11 = make_float2(cb * ca,  -sb * sa);
    float2 ph0 = make_float2(cc, -sc);  // e^{-ic/2}
    float2 ph1 = make_float2(cc,  sc);  // e^{+ic/2}
    mats[g * 4 + 0] = cmul(ph0, m00);
    mats[g * 4 + 1] = cmul(ph0, m01);
    mats[g * 4 + 2] = cmul(ph1, m10);
    mats[g * 4 + 3] = cmul(ph1, m11);
}

// Pass A: bits 0..12 local (qubits 8..20). Contiguous 8192-amp chunk per block, in-place.
// entangle: apply c2 (b12^=b13, b13 = blk&1) then C3 (b11^=b12 ... b0^=b1) as permuted LDS read at write.
// partials != nullptr: last layer -> no write-back; emit total + per-qubit "ones" partial sums.
__global__ __launch_bounds__(512) void k_passA(float2* __restrict__ psi, const float2* __restrict__ mats,
                                               int layer, int entangle, float* __restrict__ partials) {
    __shared__ float4 lds4[4096];  // 8192 complex, 64 KB
    float2* lds = (float2*)lds4;
    const int blk = blockIdx.x, tid = threadIdx.x;

    const float4* g4 = (const float4*)psi + blk * 4096;
    for (int i = tid; i < 4096; i += 512) lds4[i] = g4[i];
    __syncthreads();

    for (int k = 0; k < 13; ++k) {  // bit k -> qubit 20-k
        const float2* U = mats + (layer * NQ + (20 - k)) * 4;
        float2 u00 = U[0], u01 = U[1], u10 = U[2], u11 = U[3];
        int m = 1 << k;
        for (int p = tid; p < 4096; p += 512) {
            int i0 = ((p >> k) << (k + 1)) | (p & (m - 1));
            int i1 = i0 | m;
            float2 a = lds[i0], b = lds[i1];
            lds[i0] = cfma2(u00, a, u01, b);
            lds[i1] = cfma2(u10, a, u11, b);
        }
        __syncthreads();
    }

    if (partials) {
        float tot = 0.f;
        float ones[NQ];
#pragma unroll
        for (int q = 0; q < NQ; ++q) ones[q] = 0.f;
        for (int t = tid; t < 8192; t += 512) {
            float2 a = lds[t];
            float pr = a.x * a.x + a.y * a.y;
            int gidx = (blk << 13) | t;
            tot += pr;
#pragma unroll
            for (int q = 0; q < NQ; ++q)
                ones[q] += ((gidx >> (20 - q)) & 1) ? pr : 0.f;
        }
        // wave reduce (64 lanes)
        for (int off = 32; off; off >>= 1) {
            tot += __shfl_down(tot, off, 64);
#pragma unroll
            for (int q = 0; q < NQ; ++q) ones[q] += __shfl_down(ones[q], off, 64);
        }
        __syncthreads();  // done with state in LDS; reuse as reduction scratch
        float* red = (float*)lds4;
        int wave = tid >> 6, lane = tid & 63;
        if (lane == 0) {
            red[wave * 22 + 21] = tot;
#pragma unroll
            for (int q = 0; q < NQ; ++q) red[wave * 22 + q] = ones[q];
        }
        __syncthreads();
        if (tid < 22) {
            float s = 0.f;
            for (int w = 0; w < 8; ++w) s += red[w * 22 + tid];
            partials[blk * 22 + tid] = s;
        }
    } else if (entangle) {
        float4* o4 = (float4*)psi + blk * 4096;
        int cbit = (blk & 1) << 12;
        for (int t = tid; t < 4096; t += 512) {
            int j0 = 2 * t, j1 = j0 + 1;
            int s0 = (j0 ^ ((j0 >> 1) & 0xFFF)) ^ cbit;
            int s1 = (j1 ^ ((j1 >> 1) & 0xFFF)) ^ cbit;
            float2 e0 = lds[s0], e1 = lds[s1];
            o4[t] = make_float4(e0.x, e0.y, e1.x, e1.y);
        }
    } else {
        float4* o4 = (float4*)psi + blk * 4096;
        for (int t = tid; t < 4096; t += 512) o4[t] = lds4[t];
    }
}

// Pass B: bits 13..20 local rows (qubits 0..7) x 32 contiguous low elements; fixed bits 5..12 = blk.
// state != nullptr: first pass, read real f32 input (imag=0).
// c4: fold previous layer's CNOT(20,0) (b20 ^= b0) into the LDS scatter at load.
// c1: apply this layer's B-local chain (b19^=b20 ... b13^=b14) as row scatter at write.
__global__ __launch_bounds__(512) void k_passB(const float* __restrict__ state, float2* __restrict__ psi,
                                               const float2* __restrict__ mats, int layer, int c4, int c1) {
    __shared__ float2 lds[8192];  // [h=256][l=32], 64 KB
    const int blk = blockIdx.x, tid = threadIdx.x;

    if (state) {
        const float4* s4 = (const float4*)state;
        for (int t = tid; t < 2048; t += 512) {
            int hs = t >> 3, c = t & 7;
            float4 v = s4[(hs << 11) | (blk << 3) | c];
            int base = hs * 32 + 4 * c;
            lds[base + 0] = make_float2(v.x, 0.f);
            lds[base + 1] = make_float2(v.y, 0.f);
            lds[base + 2] = make_float2(v.z, 0.f);
            lds[base + 3] = make_float2(v.w, 0.f);
        }
    } else {
        const float4* p4 = (const float4*)psi;
        for (int t = tid; t < 4096; t += 512) {
            int hs = t >> 4, c = t & 15;
            float4 v = p4[(hs << 12) | (blk << 4) | c];
            int hodd = c4 ? (hs ^ 128) : hs;
            lds[hs * 32 + 2 * c]       = make_float2(v.x, v.y);
            lds[hodd * 32 + 2 * c + 1] = make_float2(v.z, v.w);
        }
    }
    __syncthreads();

    for (int kb = 0; kb < 8; ++kb) {  // local h-bit kb -> global bit 13+kb -> qubit 7-kb
        const float2* U = mats + (layer * NQ + (7 - kb)) * 4;
        float2 u00 = U[0], u01 = U[1], u10 = U[2], u11 = U[3];
        for (int p = tid; p < 4096; p += 512) {
            int l = p & 31, hp = p >> 5;
            int h0 = ((hp >> kb) << (kb + 1)) | (hp & ((1 << kb) - 1));
            int i0 = h0 * 32 + l;
            int i1 = i0 + (32 << kb);
            float2 a = lds[i0], b = lds[i1];
            lds[i0] = cfma2(u00, a, u01, b);
            lds[i1] = cfma2(u10, a, u11, b);
        }
        __syncthreads();
    }

    float4* o4 = (float4*)psi;
    for (int t = tid; t < 4096; t += 512) {
        int hs = t >> 4, c = t & 15;
        int hd = c1 ? pxor8(hs) : hs;
        float2 e0 = lds[hs * 32 + 2 * c], e1 = lds[hs * 32 + 2 * c + 1];
        o4[(hd << 12) | (blk << 4) | c] = make_float4(e0.x, e0.y, e1.x, e1.y);
    }
}

// Reduce partials -> meas -> head -> softmax
__global__ void k_final(const float* __restrict__ partials, const float* __restrict__ head_w,
                        const float* __restrict__ head_b, float* __restrict__ out) {
    __shared__ float red[22];
    __shared__ float meas[NQ];
    __shared__ float lg[ADIM];
    int tid = threadIdx.x;
    if (tid < 22) {
        float s = 0.f;
        for (int b = 0; b < 256; ++b) s += partials[b * 22 + tid];
        red[tid] = s;
    }
    __syncthreads();
    if (tid < NQ) {
        float tot = red[21];
        meas[tid] = (tot > 0.f) ? (1.f - 2.f * red[tid] / tot) : 1.f;
    }
    __syncthreads();
    if (tid < ADIM) {
        float s = head_b[tid];
        for (int q = 0; q < NQ; ++q) s += head_w[tid * NQ + q] * meas[q];
        lg[tid] = s;
    }
    __syncthreads();
    if (tid == 0) {
        float m = lg[0];
        for (int a = 1; a < ADIM; ++a) m = fmaxf(m, lg[a]);
        float s = 0.f;
        for (int a = 0; a < ADIM; ++a) s += expf(lg[a] - m);
        float inv = 1.f / s;
        for (int a = 0; a < ADIM; ++a) out[a] = expf(lg[a] - m) * inv;
    }
}

extern "C" void kernel_launch(void* const* d_in, const int* in_sizes, int n_in,
                              void* d_out, int out_size, void* d_ws, size_t ws_size,
                              hipStream_t stream) {
    const float* state   = (const float*)d_in[0];
    const float* cparams = (const float*)d_in[1];
    const float* head_w  = (const float*)d_in[2];
    const float* head_b  = (const float*)d_in[3];
    float* out = (float*)d_out;

    char* ws = (char*)d_ws;
    float2* psi      = (float2*)ws;
    float2* mats     = (float2*)(ws + (size_t)DIM * 8);
    float*  partials = (float*)(ws + (size_t)DIM * 8 + 4096);

    k_mats<<<1, 128, 0, stream>>>(cparams, mats);
    // layer 0
    k_passB<<<256, 512, 0, stream>>>(state,   psi, mats, 0, 0, 1);
    k_passA<<<256, 512, 0, stream>>>(psi, mats, 0, 1, nullptr);
    // layer 1
    k_passB<<<256, 512, 0, stream>>>(nullptr, psi, mats, 1, 1, 1);
    k_passA<<<256, 512, 0, stream>>>(psi, mats, 1, 1, nullptr);
    // layer 2
    k_passB<<<256, 512, 0, stream>>>(nullptr, psi, mats, 2, 1, 1);
    k_passA<<<256, 512, 0, stream>>>(psi, mats, 2, 1, nullptr);
    // layer 3 (no entangle; B3 still consumes layer2's wrap CNOT via c4)
    k_passB<<<256, 512, 0, stream>>>(nullptr, psi, mats, 3, 1, 0);
    k_passA<<<256, 512, 0, stream>>>(psi, mats, 3, 0, partials);

    k_final<<<1, 64, 0, stream>>>(partials, head_w, head_b, out);
}